// Round 1
// baseline (437.649 us; speedup 1.0000x reference)
//
#include <hip/hip_runtime.h>
#include <stdint.h>

// Problem constants (B,N,D from reference: B=8, N=16384, D=128, O=2D=256)
constexpr int Bn = 8;
constexpr int Nn = 16384;
constexpr int Dn = 128;
constexpr int On = 256;
#define LN_EPS 1e-5f

typedef float  f32x4 __attribute__((ext_vector_type(4)));
typedef short  s16x8 __attribute__((ext_vector_type(8)));

__device__ __forceinline__ unsigned short f2bf(float f) {
    union { float f; unsigned u; } v; v.f = f;
    unsigned r = v.u + 0x7FFFu + ((v.u >> 16) & 1u);   // RNE
    return (unsigned short)(r >> 16);
}
__device__ __forceinline__ float bf2f(unsigned short s) {
    unsigned u = ((unsigned)s) << 16;
    float f; __builtin_memcpy(&f, &u, 4);
    return f;
}

// ------------------------------------------------------------------
// K2: ctx[b][d][v] += sum_n exp(x1[b][n][d]) * x2[b][n][v]
//     cs[b][d]     += sum_n exp(x1[b][n][d])
// grid (64 n-chunks, 8 batches), 256 threads (4 waves). chunk = 256 n.
// ------------------------------------------------------------------
__global__ __launch_bounds__(256) void k_context(
    const float* __restrict__ x1, const float* __restrict__ x2,
    float* __restrict__ ctx, float* __restrict__ cs)
{
    __shared__ unsigned short As[128][72];  // [d][n_sub] exp(x1) bf16, pad 64->72
    __shared__ unsigned short Bs[128][72];  // [v][n_sub] x2 bf16
    __shared__ float cs_scr[256];

    const int b     = blockIdx.y;
    const int chunk = blockIdx.x;
    const int t     = threadIdx.x;
    const int wave  = t >> 6;
    const int lane  = t & 63;
    const int c     = lane & 15, g = lane >> 4;

    const int n_base = chunk * 256;

    f32x4 acc[2][8];
    #pragma unroll
    for (int i = 0; i < 2; ++i)
        #pragma unroll
        for (int j = 0; j < 8; ++j) acc[i][j] = (f32x4){0.f,0.f,0.f,0.f};

    const int nl = t >> 2;        // 0..63 local n row
    const int q  = t & 3;
    const int d0 = q * 32;

    float cs_acc = 0.f;
    const int cd = t & 127, half = t >> 7;  // colsum assignment

    for (int sc = 0; sc < 4; ++sc) {
        const int n0 = n_base + sc * 64;
        // stage: x1 -> exp -> As (transposed), x2 -> Bs (transposed)
        {
            const float* p1 = x1 + (((long)b * Nn + n0 + nl) * Dn + d0);
            const float* p2 = x2 + (((long)b * Nn + n0 + nl) * Dn + d0);
            #pragma unroll
            for (int j = 0; j < 8; ++j) {
                f32x4 v1 = *(const f32x4*)(p1 + j * 4);
                f32x4 v2 = *(const f32x4*)(p2 + j * 4);
                #pragma unroll
                for (int jj = 0; jj < 4; ++jj) {
                    int d = d0 + j * 4 + jj;
                    As[d][nl] = f2bf(__expf(v1[jj]));
                    Bs[d][nl] = f2bf(v2[jj]);
                }
            }
        }
        __syncthreads();
        // colsum partial (reads As)
        #pragma unroll
        for (int j = 0; j < 4; ++j) {
            const s16x8 e = *(const s16x8*)&As[cd][half * 32 + j * 8];
            #pragma unroll
            for (int jj = 0; jj < 8; ++jj)
                cs_acc += bf2f((unsigned short)e[jj]);
        }
        // MFMA: D[m=d][n=v] = sum_k A[d][k]*B[k][v], k = n
        #pragma unroll
        for (int kk = 0; kk < 2; ++kk) {
            s16x8 a[2], bb[8];
            #pragma unroll
            for (int mt = 0; mt < 2; ++mt)
                a[mt] = *(const s16x8*)&As[wave * 32 + mt * 16 + c][kk * 32 + g * 8];
            #pragma unroll
            for (int nt = 0; nt < 8; ++nt)
                bb[nt] = *(const s16x8*)&Bs[nt * 16 + c][kk * 32 + g * 8];
            #pragma unroll
            for (int mt = 0; mt < 2; ++mt)
                #pragma unroll
                for (int nt = 0; nt < 8; ++nt)
                    acc[mt][nt] = __builtin_amdgcn_mfma_f32_16x16x32_bf16(
                        a[mt], bb[nt], acc[mt][nt], 0, 0, 0);
        }
        __syncthreads();
    }

    // colsum reduce across the two halves, then one atomic per d
    cs_scr[t] = cs_acc;
    __syncthreads();
    if (t < 128) unsafeAtomicAdd(&cs[b * 128 + t], cs_scr[t] + cs_scr[t + 128]);

    // ctx atomics: C/D layout col=lane&15, row=(lane>>4)*4+reg
    #pragma unroll
    for (int mt = 0; mt < 2; ++mt)
        #pragma unroll
        for (int nt = 0; nt < 8; ++nt)
            #pragma unroll
            for (int r = 0; r < 4; ++r) {
                int d = wave * 32 + mt * 16 + g * 4 + r;
                int v = nt * 16 + c;
                unsafeAtomicAdd(&ctx[((long)b * 128 + d) * 128 + v], acc[mt][nt][r]);
            }
}

// ------------------------------------------------------------------
// K3: Mt[b][o][d] = bf16( (sum_v ctx[b][d][v]*w[o][v]) / cs[b][d] )
// grid (8 o-chunks, 8 batches), 256 threads. thread -> (o, 16 d's)
// ------------------------------------------------------------------
__global__ __launch_bounds__(256) void k_mt(
    const float* __restrict__ ctx, const float* __restrict__ cs,
    const float* __restrict__ w, unsigned short* __restrict__ Mt)
{
    const int b  = blockIdx.y;
    const int oc = blockIdx.x;
    const int t  = threadIdx.x;
    const int o  = oc * 32 + (t >> 3);
    const int d0 = (t & 7) * 16;

    const float* wrow  = w + (long)o * 128;
    const float* cbase = ctx + (long)b * 128 * 128;

    unsigned short outv[16];
    #pragma unroll
    for (int dd = 0; dd < 16; ++dd) {
        const int d = d0 + dd;
        const float* crow = cbase + d * 128;
        float s = 0.f;
        #pragma unroll 8
        for (int v = 0; v < 128; v += 4) {
            f32x4 cv = *(const f32x4*)(crow + v);
            f32x4 wv = *(const f32x4*)(wrow + v);
            s += cv[0]*wv[0] + cv[1]*wv[1] + cv[2]*wv[2] + cv[3]*wv[3];
        }
        outv[dd] = f2bf(s / cs[b * 128 + d]);
    }
    uint4* dst = (uint4*)(Mt + ((long)b * On + o) * 128 + d0);
    dst[0] = ((const uint4*)outv)[0];
    dst[1] = ((const uint4*)outv)[1];
}

// ------------------------------------------------------------------
// K4: out[b][n][o] = LN_o( (1/rowsum[n]) * sum_d exp(x1[b][n][d]) * Mt[o][d] + bias[o] )
// grid (256 row-blocks of 64, 8 batches), 256 threads (4 waves, 16 rows/wave)
// ------------------------------------------------------------------
__global__ __launch_bounds__(256) void k_main(
    const float* __restrict__ x1, const unsigned short* __restrict__ Mt,
    const float* __restrict__ bias, const float* __restrict__ gamma,
    const float* __restrict__ beta, float* __restrict__ out)
{
    __shared__ unsigned short As[64][136];  // [row][d] exp(x1) bf16, pad 128->136
    __shared__ float inv_rs[64];

    const int b    = blockIdx.y;
    const int n0   = blockIdx.x * 64;
    const int t    = threadIdx.x;
    const int wave = t >> 6, lane = t & 63;
    const int c    = lane & 15, g = lane >> 4;

    // stage: compute exp(x1 row), rowsum, bf16-pack to LDS
    {
        const int row = t >> 2, q = t & 3, d0 = q * 32;
        const float* p1 = x1 + (((long)b * Nn + n0 + row) * Dn + d0);
        float ev[32];
        float s = 0.f;
        #pragma unroll
        for (int j = 0; j < 8; ++j) {
            f32x4 v = *(const f32x4*)(p1 + j * 4);
            #pragma unroll
            for (int jj = 0; jj < 4; ++jj) {
                float e = __expf(v[jj]);
                ev[j * 4 + jj] = e;
                s += e;
            }
        }
        s += __shfl_xor(s, 1);
        s += __shfl_xor(s, 2);
        if (q == 0) inv_rs[row] = 1.0f / s;
        unsigned short us[32];
        #pragma unroll
        for (int j = 0; j < 32; ++j) us[j] = f2bf(ev[j]);
        uint4* dst = (uint4*)&As[row][d0];
        #pragma unroll
        for (int j = 0; j < 4; ++j) dst[j] = ((const uint4*)us)[j];
    }
    __syncthreads();

    // A fragments: A[m=row][k=d], lane holds A[m=lane&15][k=(lane>>4)*8+j]
    s16x8 a[4];
    #pragma unroll
    for (int kk = 0; kk < 4; ++kk)
        a[kk] = *(const s16x8*)&As[wave * 16 + c][kk * 32 + g * 8];

    // B from global (L2-resident, 64KB/batch): B[k=d][n=o] = Mt[o][d]
    const unsigned short* mb = Mt + (long)b * On * 128;
    f32x4 acc[16];
    #pragma unroll
    for (int nt = 0; nt < 16; ++nt) {
        acc[nt] = (f32x4){0.f,0.f,0.f,0.f};
        const unsigned short* bp = mb + (nt * 16 + c) * 128 + g * 8;
        #pragma unroll
        for (int kk = 0; kk < 4; ++kk) {
            s16x8 bb = *(const s16x8*)(bp + kk * 32);
            acc[nt] = __builtin_amdgcn_mfma_f32_16x16x32_bf16(a[kk], bb, acc[nt], 0, 0, 0);
        }
    }

    // epilogue: eff = acc*inv_rs + bias; LayerNorm over the 256 cols of each row
    float inv[4];
    #pragma unroll
    for (int r = 0; r < 4; ++r) inv[r] = inv_rs[wave * 16 + g * 4 + r];

    float sm[4] = {0,0,0,0}, ssq[4] = {0,0,0,0};
    #pragma unroll
    for (int nt = 0; nt < 16; ++nt) {
        const int col = nt * 16 + c;
        const float bv = bias[col];
        #pragma unroll
        for (int r = 0; r < 4; ++r) {
            float e = acc[nt][r] * inv[r] + bv;
            acc[nt][r] = e;
            sm[r] += e;
            ssq[r] += e * e;
        }
    }
    #pragma unroll
    for (int r = 0; r < 4; ++r) {
        #pragma unroll
        for (int off = 1; off < 16; off <<= 1) {
            sm[r]  += __shfl_xor(sm[r], off);
            ssq[r] += __shfl_xor(ssq[r], off);
        }
    }
    float mean[4], rstd[4];
    #pragma unroll
    for (int r = 0; r < 4; ++r) {
        mean[r] = sm[r] * (1.0f / 256.0f);
        float var = ssq[r] * (1.0f / 256.0f) - mean[r] * mean[r];
        rstd[r] = rsqrtf(var + LN_EPS);
    }
    #pragma unroll
    for (int nt = 0; nt < 16; ++nt) {
        const int col = nt * 16 + c;
        const float gm = gamma[col], bt = beta[col];
        #pragma unroll
        for (int r = 0; r < 4; ++r) {
            const int row = n0 + wave * 16 + g * 4 + r;
            out[((long)b * Nn + row) * On + col] = (acc[nt][r] - mean[r]) * rstd[r] * gm + bt;
        }
    }
}

extern "C" void kernel_launch(void* const* d_in, const int* in_sizes, int n_in,
                              void* d_out, int out_size, void* d_ws, size_t ws_size,
                              hipStream_t stream)
{
    const float* x1    = (const float*)d_in[0];
    const float* x2    = (const float*)d_in[1];
    const float* w     = (const float*)d_in[2];   // [256][128] (1x1 conv)
    const float* bias  = (const float*)d_in[3];   // [256]
    const float* gamma = (const float*)d_in[4];   // [256]
    const float* beta  = (const float*)d_in[5];   // [256]
    float* out = (float*)d_out;

    // ws layout: ctx [8][128][128] f32 | cs [8][128] f32 | Mt [8][256][128] bf16
    float* ctx = (float*)d_ws;
    float* cs  = (float*)((char*)d_ws + 524288);
    unsigned short* Mt = (unsigned short*)((char*)d_ws + 528384);

    hipMemsetAsync(d_ws, 0, 528384, stream);  // zero ctx + cs (atomic targets)

    k_context<<<dim3(64, 8), 256, 0, stream>>>(x1, x2, ctx, cs);
    k_mt<<<dim3(8, 8), 256, 0, stream>>>(ctx, cs, w, Mt);
    k_main<<<dim3(256, 8), 256, 0, stream>>>(x1, Mt, bias, gamma, beta, out);
}

// Round 2
// 421.244 us; speedup vs baseline: 1.0389x; 1.0389x over previous
//
#include <hip/hip_runtime.h>
#include <stdint.h>

constexpr int Bn = 8;
constexpr int Nn = 16384;
constexpr int Dn = 128;
constexpr int On = 256;
#define LN_EPS 1e-5f

typedef float  f32x4 __attribute__((ext_vector_type(4)));
typedef short  s16x8 __attribute__((ext_vector_type(8)));

__device__ __forceinline__ unsigned short f2bf(float f) {
    union { float f; unsigned u; } v; v.f = f;
    unsigned r = v.u + 0x7FFFu + ((v.u >> 16) & 1u);   // RNE
    return (unsigned short)(r >> 16);
}
__device__ __forceinline__ float bf2f(unsigned short s) {
    unsigned u = ((unsigned)s) << 16;
    float f; __builtin_memcpy(&f, &u, 4);
    return f;
}

// ------------------------------------------------------------------
// K2: ctx[b][d][v] += sum_n exp(x1[b][n][d]) * x2[b][n][v]
//     cs[b][d]     += sum_n exp(x1[b][n][d])
// grid (64 n-chunks, 8 batches), 256 threads (4 waves). chunk = 256 n.
// ------------------------------------------------------------------
__global__ __launch_bounds__(256) void k_context(
    const float* __restrict__ x1, const float* __restrict__ x2,
    float* __restrict__ ctx, float* __restrict__ cs)
{
    __shared__ unsigned short As[128][72];  // [d][n_sub] exp(x1) bf16, pad 64->72
    __shared__ unsigned short Bs[128][72];  // [v][n_sub] x2 bf16
    __shared__ float cs_scr[256];

    const int b     = blockIdx.y;
    const int chunk = blockIdx.x;
    const int t     = threadIdx.x;
    const int wave  = t >> 6;
    const int lane  = t & 63;
    const int c     = lane & 15, g = lane >> 4;

    const int n_base = chunk * 256;

    f32x4 acc[2][8];
    #pragma unroll
    for (int i = 0; i < 2; ++i)
        #pragma unroll
        for (int j = 0; j < 8; ++j) acc[i][j] = (f32x4){0.f,0.f,0.f,0.f};

    // staging: thread -> (dg 0..7 -> 16 d's, rg 0..31 -> row pair)
    // bank for As[d][2rg] b32 write = (4d + rg) % 32 -> <=2-way, conflict-free
    const int dg = t >> 5, rg = t & 31;
    const int d0 = dg * 16;

    float cs_acc = 0.f;
    const int cd = t & 127, half = t >> 7;  // colsum assignment

    for (int sc = 0; sc < 4; ++sc) {
        const int n0 = n_base + sc * 64;
        // stage: x1 -> exp -> As (transposed), x2 -> Bs (transposed), 2 rows/thread
        {
            const float* p1 = x1 + (((long)b * Nn + n0 + 2 * rg) * Dn + d0);
            const float* p2 = x2 + (((long)b * Nn + n0 + 2 * rg) * Dn + d0);
            f32x4 r1a[4], r1b[4], r2a[4], r2b[4];
            #pragma unroll
            for (int j = 0; j < 4; ++j) {
                r1a[j] = *(const f32x4*)(p1 + j * 4);
                r1b[j] = *(const f32x4*)(p1 + Dn + j * 4);
                r2a[j] = *(const f32x4*)(p2 + j * 4);
                r2b[j] = *(const f32x4*)(p2 + Dn + j * 4);
            }
            #pragma unroll
            for (int j = 0; j < 4; ++j) {
                #pragma unroll
                for (int jj = 0; jj < 4; ++jj) {
                    const int d = d0 + j * 4 + jj;
                    unsigned ua = (unsigned)f2bf(__expf(r1a[j][jj])) |
                                  ((unsigned)f2bf(__expf(r1b[j][jj])) << 16);
                    unsigned ub = (unsigned)f2bf(r2a[j][jj]) |
                                  ((unsigned)f2bf(r2b[j][jj]) << 16);
                    *(unsigned*)&As[d][2 * rg] = ua;
                    *(unsigned*)&Bs[d][2 * rg] = ub;
                }
            }
        }
        __syncthreads();
        // colsum partial (reads As)
        #pragma unroll
        for (int j = 0; j < 4; ++j) {
            const s16x8 e = *(const s16x8*)&As[cd][half * 32 + j * 8];
            #pragma unroll
            for (int jj = 0; jj < 8; ++jj)
                cs_acc += bf2f((unsigned short)e[jj]);
        }
        // MFMA: D[m=d][n=v] = sum_k A[d][k]*B[k][v], k = n
        #pragma unroll
        for (int kk = 0; kk < 2; ++kk) {
            s16x8 a[2], bb[8];
            #pragma unroll
            for (int mt = 0; mt < 2; ++mt)
                a[mt] = *(const s16x8*)&As[wave * 32 + mt * 16 + c][kk * 32 + g * 8];
            #pragma unroll
            for (int nt = 0; nt < 8; ++nt)
                bb[nt] = *(const s16x8*)&Bs[nt * 16 + c][kk * 32 + g * 8];
            #pragma unroll
            for (int mt = 0; mt < 2; ++mt)
                #pragma unroll
                for (int nt = 0; nt < 8; ++nt)
                    acc[mt][nt] = __builtin_amdgcn_mfma_f32_16x16x32_bf16(
                        a[mt], bb[nt], acc[mt][nt], 0, 0, 0);
        }
        __syncthreads();
    }

    cs_scr[t] = cs_acc;
    __syncthreads();
    if (t < 128) unsafeAtomicAdd(&cs[b * 128 + t], cs_scr[t] + cs_scr[t + 128]);

    // ctx atomics: C/D layout col=lane&15, row=(lane>>4)*4+reg
    #pragma unroll
    for (int mt = 0; mt < 2; ++mt)
        #pragma unroll
        for (int nt = 0; nt < 8; ++nt)
            #pragma unroll
            for (int r = 0; r < 4; ++r) {
                int d = wave * 32 + mt * 16 + g * 4 + r;
                int v = nt * 16 + c;
                unsafeAtomicAdd(&ctx[((long)b * 128 + d) * 128 + v], acc[mt][nt][r]);
            }
}

// ------------------------------------------------------------------
// K3: Mt[b][o][d] = bf16( (sum_v ctx[b][d][v]*w[o][v]) / cs[b][d] )
// ------------------------------------------------------------------
__global__ __launch_bounds__(256) void k_mt(
    const float* __restrict__ ctx, const float* __restrict__ cs,
    const float* __restrict__ w, unsigned short* __restrict__ Mt)
{
    const int b  = blockIdx.y;
    const int oc = blockIdx.x;
    const int t  = threadIdx.x;
    const int o  = oc * 32 + (t >> 3);
    const int d0 = (t & 7) * 16;

    const float* wrow  = w + (long)o * 128;
    const float* cbase = ctx + (long)b * 128 * 128;

    unsigned short outv[16];
    #pragma unroll
    for (int dd = 0; dd < 16; ++dd) {
        const int d = d0 + dd;
        const float* crow = cbase + d * 128;
        float s = 0.f;
        #pragma unroll 8
        for (int v = 0; v < 128; v += 4) {
            f32x4 cv = *(const f32x4*)(crow + v);
            f32x4 wv = *(const f32x4*)(wrow + v);
            s += cv[0]*wv[0] + cv[1]*wv[1] + cv[2]*wv[2] + cv[3]*wv[3];
        }
        outv[dd] = f2bf(s / cs[b * 128 + d]);
    }
    uint4* dst = (uint4*)(Mt + ((long)b * On + o) * 128 + d0);
    dst[0] = ((const uint4*)outv)[0];
    dst[1] = ((const uint4*)outv)[1];
}

// ------------------------------------------------------------------
// K4 (flipped): D[m=o][n=row].  A = Mt (m=o,k=d), B = exp(x1) (k=d,n=row).
// C/D: col=lane&15 -> row, reg r -> o = nt*16 + g*4 + r  => float4 stores.
// No LDS, no barriers. grid (256 row-blocks of 64, 8 batches), 256 thr.
// ------------------------------------------------------------------
__global__ __launch_bounds__(256) void k_main(
    const float* __restrict__ x1, const unsigned short* __restrict__ Mt,
    const float* __restrict__ bias, const float* __restrict__ gamma,
    const float* __restrict__ beta, float* __restrict__ out)
{
    const int b    = blockIdx.y;
    const int t    = threadIdx.x;
    const int wave = t >> 6, lane = t & 63;
    const int c    = lane & 15, g = lane >> 4;
    const int row  = blockIdx.x * 64 + wave * 16 + c;   // this lane's n

    // B fragments from global: B[k=d][n=row], lane holds d = kk*32 + g*8 + j
    s16x8 bfr[4];
    float rs = 0.f;
    const float* xrow = x1 + ((long)b * Nn + row) * Dn;
    #pragma unroll
    for (int kk = 0; kk < 4; ++kk) {
        const float* p = xrow + kk * 32 + g * 8;
        f32x4 v0 = *(const f32x4*)p;
        f32x4 v1 = *(const f32x4*)(p + 4);
        s16x8 bb;
        #pragma unroll
        for (int j = 0; j < 4; ++j) {
            float e0 = __expf(v0[j]), e1 = __expf(v1[j]);
            rs += e0 + e1;
            bb[j]     = (short)f2bf(e0);
            bb[j + 4] = (short)f2bf(e1);
        }
        bfr[kk] = bb;
    }
    // lanes c, c+16, c+32, c+48 hold this row's 4 d-quarters
    rs += __shfl_xor(rs, 16);
    rs += __shfl_xor(rs, 32);
    const float inv = 1.0f / rs;

    // A fragments from Mt: A[m=o][k=d], lane holds o = nt*16+c, d = kk*32+g*8+j
    const unsigned short* mb = Mt + ((long)b * On + c) * Dn + g * 8;
    f32x4 acc[16];
    #pragma unroll
    for (int nt = 0; nt < 16; ++nt) {
        const unsigned short* ap = mb + (long)nt * 16 * Dn;
        f32x4 a4 = (f32x4){0.f, 0.f, 0.f, 0.f};
        #pragma unroll
        for (int kk = 0; kk < 4; ++kk) {
            s16x8 af = *(const s16x8*)(ap + kk * 32);
            a4 = __builtin_amdgcn_mfma_f32_16x16x32_bf16(af, bfr[kk], a4, 0, 0, 0);
        }
        acc[nt] = a4;
    }

    // epilogue: eff = acc*inv + bias; LN over o (256) per row
    float sm = 0.f, ssq = 0.f;
    #pragma unroll
    for (int nt = 0; nt < 16; ++nt) {
        f32x4 bv = *(const f32x4*)(bias + nt * 16 + g * 4);
        #pragma unroll
        for (int r = 0; r < 4; ++r) {
            float e = acc[nt][r] * inv + bv[r];
            acc[nt][r] = e;
            sm += e;
            ssq += e * e;
        }
    }
    sm  += __shfl_xor(sm, 16);  sm  += __shfl_xor(sm, 32);
    ssq += __shfl_xor(ssq, 16); ssq += __shfl_xor(ssq, 32);
    const float mean = sm * (1.0f / 256.0f);
    const float rstd = rsqrtf(ssq * (1.0f / 256.0f) - mean * mean + LN_EPS);

    float* op = out + ((long)b * Nn + row) * On;
    #pragma unroll
    for (int nt = 0; nt < 16; ++nt) {
        f32x4 gm = *(const f32x4*)(gamma + nt * 16 + g * 4);
        f32x4 bt = *(const f32x4*)(beta  + nt * 16 + g * 4);
        f32x4 o;
        #pragma unroll
        for (int r = 0; r < 4; ++r)
            o[r] = (acc[nt][r] - mean) * rstd * gm[r] + bt[r];
        *(f32x4*)(op + nt * 16 + g * 4) = o;
    }
}

extern "C" void kernel_launch(void* const* d_in, const int* in_sizes, int n_in,
                              void* d_out, int out_size, void* d_ws, size_t ws_size,
                              hipStream_t stream)
{
    const float* x1    = (const float*)d_in[0];
    const float* x2    = (const float*)d_in[1];
    const float* w     = (const float*)d_in[2];
    const float* bias  = (const float*)d_in[3];
    const float* gamma = (const float*)d_in[4];
    const float* beta  = (const float*)d_in[5];
    float* out = (float*)d_out;

    float* ctx = (float*)d_ws;                                   // 8*128*128 f32
    float* cs  = (float*)((char*)d_ws + 524288);                 // 8*128 f32
    unsigned short* Mt = (unsigned short*)((char*)d_ws + 528384);// 8*256*128 bf16

    hipMemsetAsync(d_ws, 0, 528384, stream);  // zero ctx + cs (atomic targets)

    k_context<<<dim3(64, 8), 256, 0, stream>>>(x1, x2, ctx, cs);
    k_mt<<<dim3(8, 8), 256, 0, stream>>>(ctx, cs, w, Mt);
    k_main<<<dim3(256, 8), 256, 0, stream>>>(x1, Mt, bias, gamma, beta, out);
}

// Round 3
// 381.420 us; speedup vs baseline: 1.1474x; 1.1044x over previous
//
#include <hip/hip_runtime.h>
#include <stdint.h>

constexpr int Bn = 8;
constexpr int Nn = 16384;
constexpr int Dn = 128;
constexpr int On = 256;
#define LN_EPS 1e-5f

typedef float  f32x4 __attribute__((ext_vector_type(4)));
typedef short  s16x8 __attribute__((ext_vector_type(8)));

__device__ __forceinline__ unsigned short f2bf(float f) {
    union { float f; unsigned u; } v; v.f = f;
    unsigned r = v.u + 0x7FFFu + ((v.u >> 16) & 1u);   // RNE
    return (unsigned short)(r >> 16);
}
__device__ __forceinline__ float bf2f(unsigned short s) {
    unsigned u = ((unsigned)s) << 16;
    float f; __builtin_memcpy(&f, &u, 4);
    return f;
}

// ------------------------------------------------------------------
// K2: ctx[b][d][v] += sum_n exp(x1[b][n][d]) * x2[b][n][v]
//     cs[b][d]     += sum_n exp(x1[b][n][d])
// (unchanged from round 2 — not the measured bottleneck)
// ------------------------------------------------------------------
__global__ __launch_bounds__(256) void k_context(
    const float* __restrict__ x1, const float* __restrict__ x2,
    float* __restrict__ ctx, float* __restrict__ cs)
{
    __shared__ unsigned short As[128][72];
    __shared__ unsigned short Bs[128][72];
    __shared__ float cs_scr[256];

    const int b     = blockIdx.y;
    const int chunk = blockIdx.x;
    const int t     = threadIdx.x;
    const int wave  = t >> 6;
    const int lane  = t & 63;
    const int c     = lane & 15, g = lane >> 4;

    const int n_base = chunk * 256;

    f32x4 acc[2][8];
    #pragma unroll
    for (int i = 0; i < 2; ++i)
        #pragma unroll
        for (int j = 0; j < 8; ++j) acc[i][j] = (f32x4){0.f,0.f,0.f,0.f};

    const int dg = t >> 5, rg = t & 31;
    const int d0 = dg * 16;

    float cs_acc = 0.f;
    const int cd = t & 127, half = t >> 7;

    for (int sc = 0; sc < 4; ++sc) {
        const int n0 = n_base + sc * 64;
        {
            const float* p1 = x1 + (((long)b * Nn + n0 + 2 * rg) * Dn + d0);
            const float* p2 = x2 + (((long)b * Nn + n0 + 2 * rg) * Dn + d0);
            f32x4 r1a[4], r1b[4], r2a[4], r2b[4];
            #pragma unroll
            for (int j = 0; j < 4; ++j) {
                r1a[j] = *(const f32x4*)(p1 + j * 4);
                r1b[j] = *(const f32x4*)(p1 + Dn + j * 4);
                r2a[j] = *(const f32x4*)(p2 + j * 4);
                r2b[j] = *(const f32x4*)(p2 + Dn + j * 4);
            }
            #pragma unroll
            for (int j = 0; j < 4; ++j) {
                #pragma unroll
                for (int jj = 0; jj < 4; ++jj) {
                    const int d = d0 + j * 4 + jj;
                    unsigned ua = (unsigned)f2bf(__expf(r1a[j][jj])) |
                                  ((unsigned)f2bf(__expf(r1b[j][jj])) << 16);
                    unsigned ub = (unsigned)f2bf(r2a[j][jj]) |
                                  ((unsigned)f2bf(r2b[j][jj]) << 16);
                    *(unsigned*)&As[d][2 * rg] = ua;
                    *(unsigned*)&Bs[d][2 * rg] = ub;
                }
            }
        }
        __syncthreads();
        #pragma unroll
        for (int j = 0; j < 4; ++j) {
            const s16x8 e = *(const s16x8*)&As[cd][half * 32 + j * 8];
            #pragma unroll
            for (int jj = 0; jj < 8; ++jj)
                cs_acc += bf2f((unsigned short)e[jj]);
        }
        #pragma unroll
        for (int kk = 0; kk < 2; ++kk) {
            s16x8 a[2], bb[8];
            #pragma unroll
            for (int mt = 0; mt < 2; ++mt)
                a[mt] = *(const s16x8*)&As[wave * 32 + mt * 16 + c][kk * 32 + g * 8];
            #pragma unroll
            for (int nt = 0; nt < 8; ++nt)
                bb[nt] = *(const s16x8*)&Bs[nt * 16 + c][kk * 32 + g * 8];
            #pragma unroll
            for (int mt = 0; mt < 2; ++mt)
                #pragma unroll
                for (int nt = 0; nt < 8; ++nt)
                    acc[mt][nt] = __builtin_amdgcn_mfma_f32_16x16x32_bf16(
                        a[mt], bb[nt], acc[mt][nt], 0, 0, 0);
        }
        __syncthreads();
    }

    cs_scr[t] = cs_acc;
    __syncthreads();
    if (t < 128) unsafeAtomicAdd(&cs[b * 128 + t], cs_scr[t] + cs_scr[t + 128]);

    #pragma unroll
    for (int mt = 0; mt < 2; ++mt)
        #pragma unroll
        for (int nt = 0; nt < 8; ++nt)
            #pragma unroll
            for (int r = 0; r < 4; ++r) {
                int d = wave * 32 + mt * 16 + g * 4 + r;
                int v = nt * 16 + c;
                unsafeAtomicAdd(&ctx[((long)b * 128 + d) * 128 + v], acc[mt][nt][r]);
            }
}

// ------------------------------------------------------------------
// K3: Mt[b][o][d] = bf16( (sum_v ctx[b][d][v]*w[o][v]) / cs[b][d] )
// ------------------------------------------------------------------
__global__ __launch_bounds__(256) void k_mt(
    const float* __restrict__ ctx, const float* __restrict__ cs,
    const float* __restrict__ w, unsigned short* __restrict__ Mt)
{
    const int b  = blockIdx.y;
    const int oc = blockIdx.x;
    const int t  = threadIdx.x;
    const int o  = oc * 32 + (t >> 3);
    const int d0 = (t & 7) * 16;

    const float* wrow  = w + (long)o * 128;
    const float* cbase = ctx + (long)b * 128 * 128;

    unsigned short outv[16];
    #pragma unroll
    for (int dd = 0; dd < 16; ++dd) {
        const int d = d0 + dd;
        const float* crow = cbase + d * 128;
        float s = 0.f;
        #pragma unroll 8
        for (int v = 0; v < 128; v += 4) {
            f32x4 cv = *(const f32x4*)(crow + v);
            f32x4 wv = *(const f32x4*)(wrow + v);
            s += cv[0]*wv[0] + cv[1]*wv[1] + cv[2]*wv[2] + cv[3]*wv[3];
        }
        outv[dd] = f2bf(s / cs[b * 128 + d]);
    }
    uint4* dst = (uint4*)(Mt + ((long)b * On + o) * 128 + d0);
    dst[0] = ((const uint4*)outv)[0];
    dst[1] = ((const uint4*)outv)[1];
}

// ------------------------------------------------------------------
// K4 v3: Mt staged in LDS (64 KiB, XOR-swizzled), 512-thread blocks.
// D[m=o][n=row]. A = Mt (m=o,k=d) from LDS, B = exp(x1) from global.
// Swizzle: 16B chunk kc of row o stored at kc ^ (o&15)  ->
//   fragment ds_read_b128: 2 lanes/bank-window (wave64-b128 floor, free)
//   staging ds_write_b128: 8 lanes/window (b128 floor, free)
// grid (128 row-blocks of 128, 8 batches), 512 threads (8 waves).
// ------------------------------------------------------------------
__global__ __launch_bounds__(512, 4) void k_main(
    const float* __restrict__ x1, const unsigned short* __restrict__ Mt,
    const float* __restrict__ bias, const float* __restrict__ gamma,
    const float* __restrict__ beta, float* __restrict__ out)
{
    __shared__ unsigned short MtL[256 * 128];   // 64 KiB

    const int b    = blockIdx.y;
    const int t    = threadIdx.x;
    const int wave = t >> 6, lane = t & 63;
    const int c    = lane & 15, g = lane >> 4;
    const int row  = blockIdx.x * 128 + wave * 16 + c;

    // ---- stage Mt -> LDS (swizzled), 8 iters x 8 KiB ----
    {
        const unsigned short* mg = Mt + (long)b * On * Dn;
        uint4 vbuf[8];
        #pragma unroll
        for (int i = 0; i < 8; ++i)
            vbuf[i] = *(const uint4*)(mg + (i * 512 + t) * 8);
        #pragma unroll
        for (int i = 0; i < 8; ++i) {
            const int ch = i * 512 + t;
            const int o = ch >> 4, kc = ch & 15;
            *(uint4*)&MtL[o * 128 + ((kc ^ (o & 15)) * 8)] = vbuf[i];
        }
    }

    // ---- B fragments from x1 (independent of LDS) ----
    s16x8 bfr[4];
    float rs = 0.f;
    const float* xrow = x1 + ((long)b * Nn + row) * Dn;
    #pragma unroll
    for (int kk = 0; kk < 4; ++kk) {
        const float* p = xrow + kk * 32 + g * 8;
        f32x4 v0 = *(const f32x4*)p;
        f32x4 v1 = *(const f32x4*)(p + 4);
        s16x8 bb;
        #pragma unroll
        for (int j = 0; j < 4; ++j) {
            float e0 = __expf(v0[j]), e1 = __expf(v1[j]);
            rs += e0 + e1;
            bb[j]     = (short)f2bf(e0);
            bb[j + 4] = (short)f2bf(e1);
        }
        bfr[kk] = bb;
    }
    rs += __shfl_xor(rs, 16);
    rs += __shfl_xor(rs, 32);
    const float inv = 1.0f / rs;

    __syncthreads();

    // ---- MFMA: A from LDS ----
    f32x4 acc[16];
    #pragma unroll
    for (int nt = 0; nt < 16; ++nt) {
        const int o = nt * 16 + c;
        const unsigned short* ap = &MtL[o * 128];
        f32x4 a4 = (f32x4){0.f, 0.f, 0.f, 0.f};
        #pragma unroll
        for (int kk = 0; kk < 4; ++kk) {
            s16x8 af = *(const s16x8*)(ap + (((kk * 4 + g) ^ c) * 8));
            a4 = __builtin_amdgcn_mfma_f32_16x16x32_bf16(af, bfr[kk], a4, 0, 0, 0);
        }
        acc[nt] = a4;
    }

    // ---- epilogue: eff = acc*inv + bias; LN over o (256) per row ----
    float sm = 0.f, ssq = 0.f;
    #pragma unroll
    for (int nt = 0; nt < 16; ++nt) {
        f32x4 bv = *(const f32x4*)(bias + nt * 16 + g * 4);
        #pragma unroll
        for (int r = 0; r < 4; ++r) {
            float e = acc[nt][r] * inv + bv[r];
            acc[nt][r] = e;
            sm += e;
            ssq += e * e;
        }
    }
    sm  += __shfl_xor(sm, 16);  sm  += __shfl_xor(sm, 32);
    ssq += __shfl_xor(ssq, 16); ssq += __shfl_xor(ssq, 32);
    const float mean = sm * (1.0f / 256.0f);
    const float rstd = rsqrtf(ssq * (1.0f / 256.0f) - mean * mean + LN_EPS);

    float* op = out + ((long)b * Nn + row) * On;
    #pragma unroll
    for (int nt = 0; nt < 16; ++nt) {
        f32x4 gm = *(const f32x4*)(gamma + nt * 16 + g * 4);
        f32x4 bt = *(const f32x4*)(beta  + nt * 16 + g * 4);
        f32x4 o;
        #pragma unroll
        for (int r = 0; r < 4; ++r)
            o[r] = (acc[nt][r] - mean) * rstd * gm[r] + bt[r];
        *(f32x4*)(op + nt * 16 + g * 4) = o;
    }
}

extern "C" void kernel_launch(void* const* d_in, const int* in_sizes, int n_in,
                              void* d_out, int out_size, void* d_ws, size_t ws_size,
                              hipStream_t stream)
{
    const float* x1    = (const float*)d_in[0];
    const float* x2    = (const float*)d_in[1];
    const float* w     = (const float*)d_in[2];
    const float* bias  = (const float*)d_in[3];
    const float* gamma = (const float*)d_in[4];
    const float* beta  = (const float*)d_in[5];
    float* out = (float*)d_out;

    float* ctx = (float*)d_ws;                                   // 8*128*128 f32
    float* cs  = (float*)((char*)d_ws + 524288);                 // 8*128 f32
    unsigned short* Mt = (unsigned short*)((char*)d_ws + 528384);// 8*256*128 bf16

    hipMemsetAsync(d_ws, 0, 528384, stream);  // zero ctx + cs (atomic targets)

    k_context<<<dim3(64, 8), 256, 0, stream>>>(x1, x2, ctx, cs);
    k_mt<<<dim3(8, 8), 256, 0, stream>>>(ctx, cs, w, Mt);
    k_main<<<dim3(128, 8), 512, 0, stream>>>(x1, Mt, bias, gamma, beta, out);
}